// Round 1
// baseline (75.280 us; speedup 1.0000x reference)
//
#include <hip/hip_runtime.h>

// STN forward: out[b,c,d,h,w] = trilinear sample of image[b,c] at
// (d,h,w) + ddf[b,:,d,h,w], border-clamped. fp32 in/out.
// image: [B,C,D,H,W], ddf: [B,3,D,H,W], out: [B,C,D,H,W]

constexpr int B = 2, C = 2, D = 128, H = 128, W = 128;
constexpr int HW  = H * W;
constexpr int DHW = D * HW;

__global__ __launch_bounds__(256) void stn_fwd_kernel(
    const float* __restrict__ image,
    const float* __restrict__ ddf,
    float* __restrict__ out)
{
    int tid = blockIdx.x * blockDim.x + threadIdx.x;   // 0 .. B*DHW-1
    if (tid >= B * DHW) return;

    int b = tid >> 21;            // / DHW  (DHW = 2^21)
    int s = tid & (DHW - 1);      // spatial index d*HW + h*W + w
    int d = s >> 14;              // / HW   (HW = 2^14)
    int r = s & (HW - 1);
    int h = r >> 7;               // / W
    int w = r & (W - 1);

    const float* ddfb = ddf + b * 3 * DHW + s;
    float cd = (float)d + ddfb[0 * DHW];
    float ch = (float)h + ddfb[1 * DHW];
    float cw = (float)w + ddfb[2 * DHW];

    // border padding: clamp to [0, dim-1]
    cd = fminf(fmaxf(cd, 0.0f), (float)(D - 1));
    ch = fminf(fmaxf(ch, 0.0f), (float)(H - 1));
    cw = fminf(fmaxf(cw, 0.0f), (float)(W - 1));

    float d0f = floorf(cd), h0f = floorf(ch), w0f = floorf(cw);
    float fd = cd - d0f, fh = ch - h0f, fw = cw - w0f;

    int d0 = (int)d0f, h0 = (int)h0f, w0 = (int)w0f;
    int d1 = min(d0 + 1, D - 1);
    int h1 = min(h0 + 1, H - 1);
    int w1 = min(w0 + 1, W - 1);

    float gd0 = 1.0f - fd, gh0 = 1.0f - fh, gw0 = 1.0f - fw;
    float w000 = gd0 * gh0 * gw0;
    float w001 = gd0 * gh0 * fw;
    float w010 = gd0 * fh  * gw0;
    float w011 = gd0 * fh  * fw;
    float w100 = fd  * gh0 * gw0;
    float w101 = fd  * gh0 * fw;
    float w110 = fd  * fh  * gw0;
    float w111 = fd  * fh  * fw;

    int p00 = d0 * HW + h0 * W;
    int p01 = d0 * HW + h1 * W;
    int p10 = d1 * HW + h0 * W;
    int p11 = d1 * HW + h1 * W;

    int o000 = p00 + w0, o001 = p00 + w1;
    int o010 = p01 + w0, o011 = p01 + w1;
    int o100 = p10 + w0, o101 = p10 + w1;
    int o110 = p11 + w0, o111 = p11 + w1;

    const float* img0 = image + (b * C + 0) * DHW;
    const float* img1 = image + (b * C + 1) * DHW;

    float v0 = img0[o000] * w000 + img0[o001] * w001
             + img0[o010] * w010 + img0[o011] * w011
             + img0[o100] * w100 + img0[o101] * w101
             + img0[o110] * w110 + img0[o111] * w111;

    float v1 = img1[o000] * w000 + img1[o001] * w001
             + img1[o010] * w010 + img1[o011] * w011
             + img1[o100] * w100 + img1[o101] * w101
             + img1[o110] * w110 + img1[o111] * w111;

    out[(b * C + 0) * DHW + s] = v0;
    out[(b * C + 1) * DHW + s] = v1;
}

extern "C" void kernel_launch(void* const* d_in, const int* in_sizes, int n_in,
                              void* d_out, int out_size, void* d_ws, size_t ws_size,
                              hipStream_t stream) {
    const float* image = (const float*)d_in[0];
    const float* ddf   = (const float*)d_in[1];
    float* out = (float*)d_out;

    int total = B * DHW;                   // threads: one per (b, spatial)
    int block = 256;
    int grid  = (total + block - 1) / block;  // 16384 blocks
    stn_fwd_kernel<<<grid, block, 0, stream>>>(image, ddf, out);
}